// Round 13
// baseline (215.147 us; speedup 1.0000x reference)
//
#include <hip/hip_runtime.h>
#include <hip/hip_bf16.h>

#define S_LEN 50
#define BATCH 128
#define DIM 256
#define NITEMS 50001
#define NPAD 50048
#define GDIM 768
#define NSEQ 6400  // S_LEN*BATCH

typedef __attribute__((ext_vector_type(8))) short short8;
typedef __attribute__((ext_vector_type(4))) short short4_;
typedef __attribute__((ext_vector_type(4))) float float4_;

static __device__ __forceinline__ unsigned short f2bf(float x){
  union { float f; unsigned u; } v; v.f = x;
  unsigned r = v.u + 0x7FFFu + ((v.u >> 16) & 1u);
  return (unsigned short)(r >> 16);
}
static __device__ __forceinline__ float bf2f(unsigned short h){
  union { unsigned u; float f; } v; v.u = ((unsigned)h) << 16;
  return v.f;
}
static __device__ __forceinline__ float rcpf_(float x){ return __builtin_amdgcn_rcpf(x); }
static __device__ __forceinline__ float exp2f_(float x){ return __builtin_amdgcn_exp2f(x); }

// ============ merged k_gi: prep absorbed ============
// blocks [0,1800): gi = x@W_ih + biases. p=bid/600, yy=(bid%600)/6, nb=bid%6.
//   A-frags built in regs via direct gathers from emb f32 (once, reused 64 MFMA);
//   B-tiles (8) staged to LDS from wih f32 with inline f2bf (wih L2-resident).
// blocks [1800,2376): whh f32->bf16 (row-major, for k_rnn).
// blocks [2376,2476): cfb (concen softmax gate).
// gi2 elem: X*12288 + (g*16 + wc*2 + tt)*256 + lane*4 + i, X=(p*S+s)*8+slice.
__global__ __launch_bounds__(256) void k_gi(const int* __restrict__ seq,
        const float* __restrict__ emb, const float* __restrict__ embp,
        const float* __restrict__ wih, const float* __restrict__ whh,
        const float* __restrict__ bih, const float* __restrict__ bhh,
        unsigned short* __restrict__ gi2, unsigned short* __restrict__ whh_bf,
        float* __restrict__ cfb){
  extern __shared__ unsigned short sB[];   // 32768 elems = 64 KB (gi blocks only)
  int bid = blockIdx.x;
  int tid = threadIdx.x;
  if (bid >= 2376){
    // ---- cfb: concen softmax, 64 wids per block ----
    int bx = bid - 2376;
    int wv = tid >> 6, lane = tid & 63;
    const float4_* pp = (const float4_*)embp;
    float4_ e0 = pp[lane], e1 = pp[64+lane], e2 = pp[128+lane];
    for (int it = 0; it < 16; ++it){
      int wid = bx*64 + wv*16 + it;
      int s = wid >> 7, b = wid & 127;
      int item = seq[s*BATCH + b];
      float4_ v = ((const float4_*)(emb + (size_t)item*DIM))[lane];
      float d0=0.f,d1=0.f,d2=0.f;
      #pragma unroll
      for (int j=0;j<4;j++){ d0 += v[j]*e0[j]; d1 += v[j]*e1[j]; d2 += v[j]*e2[j]; }
      #pragma unroll
      for (int off=32; off; off>>=1){ d0 += __shfl_xor(d0,off); d1 += __shfl_xor(d1,off); d2 += __shfl_xor(d2,off); }
      if (lane == 0){
        float m = fmaxf(d0, fmaxf(d1,d2));
        float a0 = __expf((d0-m)*10.f), a1 = __expf((d1-m)*10.f), a2 = __expf((d2-m)*10.f);
        float inv = (item != 0) ? rcpf_(a0+a1+a2) : 0.f;
        float c0 = a0*inv, c1 = a1*inv, c2 = a2*inv;
        cfb[wid]          = (c0 >= 0.01f) ? c0 : 0.f;
        cfb[NSEQ + wid]   = (c1 >= 0.01f) ? c1 : 0.f;
        cfb[2*NSEQ + wid] = (c2 >= 0.01f) ? c2 : 0.f;
      }
    }
    return;
  }
  if (bid >= 1800){
    // ---- whh conversion (row-major) ----
    int i = (bid - 1800)*256 + tid;      // 147456 float4s
    float4_ y = ((const float4_*)whh)[i];
    short4_ v;
    #pragma unroll
    for (int j=0;j<4;j++) v[j] = (short)f2bf(y[j]);
    ((short4_*)whh_bf)[i] = v;
    return;
  }
  // ---- gi ----
  int p   = bid / 600;
  int rem = bid % 600;
  int yy  = rem / 6;
  int nb  = rem % 6;
  int wv = tid >> 6;
  int lane = tid & 63;
  int col = lane & 15, q = lane >> 4;
  // B-stage: 8 tiles from wih f32, frag layout. chunk c: nt=c>>9, kf=(c>>6)&7, l=c&63
  for (int r = 0; r < 16; ++r){
    int c = r*256 + tid;                 // 0..4095
    int nt = c >> 9, kf = (c >> 6) & 7, l = c & 63;
    const float* src = wih + ((size_t)p*GDIM + (size_t)(nb*8 + nt)*16 + (l & 15))*DIM
                           + kf*32 + (l >> 4)*8;
    float4_ f0 = *(const float4_*)(src);
    float4_ f1 = *(const float4_*)(src + 4);
    short8 o;
    #pragma unroll
    for (int j=0;j<4;j++){ o[j] = (short)f2bf(f0[j]); o[4+j] = (short)f2bf(f1[j]); }
    *(short8*)(sB + (size_t)c*8) = o;
  }
  // A-frags in registers: lane holds row mt*16+col, dims kf*32 + q*8 + 0..7
  int mt = yy*4 + wv;
  int wid = mt*16 + col;
  int item = seq[(wid >> 7)*BATCH + (wid & 127)];
  const float* xr = emb + (size_t)item*DIM + q*8;
  short8 Af[8];
  #pragma unroll
  for (int kf=0; kf<8; kf++){
    float4_ f0 = *(const float4_*)(xr + kf*32);
    float4_ f1 = *(const float4_*)(xr + kf*32 + 4);
    #pragma unroll
    for (int j=0;j<4;j++){ Af[kf][j] = (short)f2bf(f0[j]); Af[kf][4+j] = (short)f2bf(f1[j]); }
  }
  __syncthreads();
  float4_ z4 = {0.f,0.f,0.f,0.f};
  float4_ acc[8];
  #pragma unroll
  for (int t=0;t<8;t++) acc[t] = z4;
  #pragma unroll
  for (int kf=0; kf<8; kf++){
    #pragma unroll
    for (int nt=0; nt<8; nt++){
      short8 bb = *(const short8*)(sB + ((nt*8 + kf)*64 + lane)*8);
      acc[nt] = __builtin_amdgcn_mfma_f32_16x16x32_bf16(Af[kf], bb, acc[nt], 0, 0, 0);
    }
  }
  int s     = yy >> 1;
  int slice = (yy & 1)*4 + wv;
  size_t X = (size_t)(p*S_LEN + s)*8 + slice;
  int g = nb >> 1;                       // gate, uniform per block
  #pragma unroll
  for (int nt=0; nt<8; nt++){
    int nn = nb*8 + nt;                  // n/16
    int wc = (nn >> 1) & 7;              // consumer wave
    int tt = nn & 1;
    int n  = nn*16 + col;
    float bv = bih[p*GDIM + n] + ((g < 2) ? bhh[p*GDIM + n] : 0.f);
    short4_ ov;
    #pragma unroll
    for (int i=0;i<4;i++) ov[i] = (short)f2bf(acc[nt][i] + bv);
    *(short4_*)(gi2 + X*12288 + (size_t)(g*16 + wc*2 + tt)*256 + lane*4) = ov;
  }
}

// ---------------- k_rnn (+ folded embT/tcw on blocks >= 24) — r11/r12 proven ----------------
__global__ __launch_bounds__(512) __attribute__((amdgpu_waves_per_eu(2, 2)))
void k_rnn(const unsigned short* __restrict__ whh_bf,
         const unsigned short* __restrict__ gi2, const float* __restrict__ bhh,
         const float* __restrict__ cfb, unsigned short* __restrict__ hnT,
         const float* __restrict__ emb, const float* __restrict__ embp,
         unsigned short* __restrict__ embT, float* __restrict__ tcw){
  extern __shared__ char lds[];
  int bid = blockIdx.x;
  int tid = threadIdx.x;
  if (bid >= 24){
    // ---- embT (B-frag) + tcw, 32 rows per 512-thr block ----
    int sub = tid >> 8;
    int t2  = tid & 255;
    unsigned short* sT = (unsigned short*)lds + sub*8192;
    int w = t2 >> 6, lane = t2 & 63;
    int r16 = w*4 + (lane >> 4);
    int c0  = lane & 15;
    int bx2 = (bid - 24)*2 + sub;        // 0..3127
    int row = bx2*16 + r16;
    bool valid = row < NITEMS;
    const float4_* er = (const float4_*)(emb + (size_t)row*DIM);
    const float4_* pp = (const float4_*)embp;
    float d0=0.f, d1=0.f, d2=0.f;
    #pragma unroll
    for (int k=0;k<4;k++){
      float4_ v = valid ? er[k*16 + c0] : float4_{0.f,0.f,0.f,0.f};
      short4_ o;
      #pragma unroll
      for (int jj=0;jj<4;jj++) o[jj] = (short)f2bf(v[jj]);
      int di = k*64 + c0*4;
      int kf = di >> 5, qd = (di >> 3) & 3, j = di & 7;
      *(short4_*)(sT + (kf*64 + r16 + qd*16)*8 + j) = o;
      float4_ e0 = pp[k*16 + c0], e1 = pp[64 + k*16 + c0], e2 = pp[128 + k*16 + c0];
      #pragma unroll
      for (int jj=0;jj<4;jj++){ d0 += v[jj]*e0[jj]; d1 += v[jj]*e1[jj]; d2 += v[jj]*e2[jj]; }
    }
    #pragma unroll
    for (int off=1; off<16; off<<=1){
      d0 += __shfl_xor(d0,off); d1 += __shfl_xor(d1,off); d2 += __shfl_xor(d2,off);
    }
    if (c0 == 0 && valid){
      float m = fmaxf(d0, fmaxf(d1,d2));
      float a0 = __expf(d0-m), a1 = __expf(d1-m), a2 = __expf(d2-m);
      float inv = rcpf_(a0+a1+a2);
      tcw[row*3+0] = a0*inv; tcw[row*3+1] = a1*inv; tcw[row*3+2] = a2*inv;
    }
    __syncthreads();
    unsigned short* dst = embT + (size_t)bx2*4096 + t2*16;
    *(short8*)(dst)     = *(const short8*)(sT + t2*16);
    *(short8*)(dst + 8) = *(const short8*)(sT + t2*16 + 8);
    return;
  }
  // ---- PSRU recurrence (r9 config, unchanged) ----
  float* cfs = (float*)(lds + 147456);
  int p  = bid >> 3;
  int slice = bid & 7;
  int b0 = slice * 16;
  int w = tid >> 6, lane = tid & 63;
  int col = lane & 15;
  int q = lane >> 4;
  int kq = q * 8;
  const unsigned short* Wp = whh_bf + (size_t)p*GDIM*DIM;

  for (int i = tid; i < 8192; i += 512) ((unsigned short*)lds)[i] = 0;
  for (int i = tid; i < 800; i += 512) cfs[i] = cfb[p*NSEQ + (i>>4)*BATCH + b0 + (i&15)];
  {
    const unsigned short* Wn = Wp + (size_t)512*DIM;
    #pragma unroll
    for (int r = 0; r < 16; r++){
      int j = r*512 + tid;          // 0..8191
      int kf = j >> 10, row = (j >> 2) & 255, qs = j & 3;
      short8 v = *(const short8*)(Wn + (size_t)row*DIM + kf*32 + ((qs ^ ((row>>1)&3)) << 3));
      *(short8*)(lds + 16384 + j*16) = v;
    }
  }

  float bias_n0 = bhh[p*GDIM + 512 + w*32 + col];
  float bias_n1 = bhh[p*GDIM + 512 + w*32 + 16 + col];

  short8 Bf[8][4];
  #pragma unroll
  for (int kf=0; kf<8; kf++){
    #pragma unroll
    for (int t=0;t<4;t++){
      int gc = (t>>1)*256 + w*32 + (t&1)*16 + col;
      Bf[kf][t] = *(const short8*)(Wp + ((size_t)gc << 8) + kf*32 + kq);
      asm volatile("" : "+a"(Bf[kf][t]));
    }
  }
  const char* wn0 = lds + 16384 + (size_t)(w*32 + col)*64 + ((q ^ ((col>>1)&3)) << 4);
  const char* wn1 = wn0 + 16*64;
  int swz  = (lane & 7) << 4;   // h-buffer swizzle (row = col)
  float hreg[2][4];
  #pragma unroll
  for (int t=0;t<2;t++){
    #pragma unroll
    for (int i=0;i<4;i++) hreg[t][i] = 0.f;
  }
  const size_t GSTRIDE = (size_t)8*12288;
  const unsigned short* gbase =
      gi2 + ((size_t)p*S_LEN*8 + slice)*12288 + (size_t)(w*2)*256 + lane*4;
  short4_ cur[6], nxt[6];
  #pragma unroll
  for (int t=0;t<6;t++)
    cur[t] = *(const short4_*)(gbase + (t>>1)*4096 + (t&1)*256);
  __syncthreads();

  const float K1 = -1.442695041f;   // -log2(e)
  const float K2 =  2.885390082f;   // 2*log2(e)
  float4_ z4 = {0.f,0.f,0.f,0.f};
  for (int s = 0; s < S_LEN; s++){
    int rbuf = s & 1, wbuf = rbuf ^ 1;
    int sn = (s+1 < S_LEN) ? s+1 : 0;
    const unsigned short* gnp = gbase + (size_t)sn*GSTRIDE;
    #pragma unroll
    for (int t=0;t<6;t++)
      nxt[t] = *(const short4_*)(gnp + (t>>1)*4096 + (t&1)*256);
    float4_ acc[6];
    #pragma unroll
    for (int t=0;t<6;t++) acc[t] = z4;
    const char* hrow = lds + rbuf*8192 + col*512;
    #pragma unroll
    for (int kf=0; kf<8; kf++){
      int ko = (kf*64 + q*16);
      short8 a = *(const short8*)(hrow + (ko ^ swz));
      #pragma unroll
      for (int t=0;t<4;t++)
        acc[t] = __builtin_amdgcn_mfma_f32_16x16x32_bf16(a, Bf[kf][t], acc[t], 0, 0, 0);
      short8 b4 = *(const short8*)(wn0 + kf*16384);
      acc[4] = __builtin_amdgcn_mfma_f32_16x16x32_bf16(a, b4, acc[4], 0, 0, 0);
      short8 b5 = *(const short8*)(wn1 + kf*16384);
      acc[5] = __builtin_amdgcn_mfma_f32_16x16x32_bf16(a, b5, acc[5], 0, 0, 0);
    }
    float4_ cfv = *(const float4_*)(cfs + s*16 + 4*q);
    char* wbase = lds + wbuf*8192;
    int d0b = 2*(w*32 + col);
    #pragma unroll
    for (int i=0;i<4;i++){
      int rb = 4*q + i;
      float hy01[2];
      #pragma unroll
      for (int t=0;t<2;t++){
        float bn = t ? bias_n1 : bias_n0;
        float r = rcpf_(1.f + exp2f_(K1*(bf2f((unsigned short)cur[t][i])   + acc[t][i])));
        float z = rcpf_(1.f + exp2f_(K1*(bf2f((unsigned short)cur[2+t][i]) + acc[2+t][i])));
        float pre = bf2f((unsigned short)cur[4+t][i]) + r*(acc[4+t][i] + bn);
        float n = 1.f - 2.f*rcpf_(exp2f_(K2*pre) + 1.f);
        float ho = hreg[t][i];
        float hy = ho - cfv[i]*z*(ho - n);
        hreg[t][i] = hy;
        hy01[t] = hy;
      }
      unsigned pk;
      asm("v_cvt_pk_bf16_f32 %0, %1, %2" : "=v"(pk) : "v"(hy01[0]), "v"(hy01[1]));
      char* rowp = wbase + rb*512;
      int sw = (rb & 7) << 4;
      *(unsigned short*)(rowp + (d0b ^ sw))        = (unsigned short)pk;
      *(unsigned short*)(rowp + ((d0b + 32) ^ sw)) = (unsigned short)(pk >> 16);
    }
    #pragma unroll
    for (int t=0;t<6;t++) cur[t] = nxt[t];
    __syncthreads();
  }
  // final hidden state -> hnT in MFMA-A-frag layout
  #pragma unroll
  for (int t=0; t<2; t++){
    int d  = w*32 + t*16 + col;
    int kf = d >> 5;
    int qd = (d >> 3) & 3;
    int j  = d & 7;
    #pragma unroll
    for (int i=0; i<4; i++){
      int rb = 4*q + i;
      hnT[(((size_t)p*8 + slice)*8 + kf)*512 + (size_t)(rb + qd*16)*8 + j] = f2bf(hreg[t][i]);
    }
  }
}

// ---------------- k_score: scores = sum_p tcw[t,p] * (hn_p @ emb.T) ----------------
__global__ __launch_bounds__(256) void k_score(const unsigned short* __restrict__ embT,
        const unsigned short* __restrict__ hnT, const float* __restrict__ tcw,
        float* __restrict__ out){
  __shared__ float sm[64*129];
  int w = threadIdx.x >> 6, lane = threadIdx.x & 63;
  int col = lane & 15, q = lane >> 4;
  int t16 = blockIdx.x*4 + w;
  int trow = t16*16 + col;
  float4_ z4 = {0.f,0.f,0.f,0.f};
  float4_ acc[3][8];
  #pragma unroll
  for (int p=0;p<3;p++){
    #pragma unroll
    for (int m=0;m<8;m++) acc[p][m] = z4;
  }
  #pragma unroll
  for (int kf=0; kf<8; kf++){
    short8 bb = *(const short8*)(embT + (((size_t)t16*8 + kf)*64 + lane)*8);
    #pragma unroll
    for (int p=0;p<3;p++){
      #pragma unroll
      for (int m=0;m<8;m++){
        short8 a = *(const short8*)(hnT + ((((size_t)p*8 + m)*8 + kf)*512) + lane*8);
        acc[p][m] = __builtin_amdgcn_mfma_f32_16x16x32_bf16(a, bb, acc[p][m], 0, 0, 0);
      }
    }
  }
  float w0=0.f, w1=0.f, w2=0.f;
  if (trow < NITEMS){ w0 = tcw[trow*3+0]; w1 = tcw[trow*3+1]; w2 = tcw[trow*3+2]; }
  #pragma unroll
  for (int m=0;m<8;m++){
    #pragma unroll
    for (int i=0;i<4;i++){
      sm[(w*16 + col)*129 + m*16 + 4*q + i] =
          w0*acc[0][m][i] + w1*acc[1][m][i] + w2*acc[2][m][i];
    }
  }
  __syncthreads();
  int trowW = blockIdx.x*64 + lane;
  if (trowW < NITEMS){
    float* orow = out + trowW;
    #pragma unroll 4
    for (int c=0; c<32; c++){
      int b = w*32 + c;
      orow[(size_t)b*NITEMS] = sm[lane*129 + b];
    }
  }
}

extern "C" void kernel_launch(void* const* d_in, const int* in_sizes, int n_in,
                              void* d_out, int out_size, void* d_ws, size_t ws_size,
                              hipStream_t stream) {
  const int*   seq  = (const int*)d_in[0];
  const float* emb  = (const float*)d_in[1];
  const float* embp = (const float*)d_in[2];
  const float* wih  = (const float*)d_in[3];
  const float* whh  = (const float*)d_in[4];
  const float* bih  = (const float*)d_in[5];
  const float* bhh  = (const float*)d_in[6];
  float* out = (float*)d_out;

  char* ws = (char*)d_ws;
  size_t off = 0;
  auto alloc = [&](size_t bytes) -> void* {
    void* r = ws + off; off += (bytes + 255) & ~(size_t)255; return r;
  };
  unsigned short* embT   = (unsigned short*)alloc((size_t)NPAD*DIM*2);
  unsigned short* whh_bf = (unsigned short*)alloc((size_t)3*GDIM*DIM*2);
  unsigned short* gi2    = (unsigned short*)alloc((size_t)3*NSEQ*GDIM*2);
  float* tcw = (float*)alloc((size_t)NITEMS*3*4);
  float* cfb = (float*)alloc((size_t)3*NSEQ*4);
  unsigned short* hnT = (unsigned short*)alloc((size_t)3*BATCH*DIM*2);

  (void)hipFuncSetAttribute((const void*)k_gi,
        hipFuncAttributeMaxDynamicSharedMemorySize, 65536);
  k_gi<<<2476, 256, 65536, stream>>>(seq, emb, embp, wih, whh, bih, bhh,
                                     gi2, whh_bf, cfb);

  (void)hipFuncSetAttribute((const void*)k_rnn,
        hipFuncAttributeMaxDynamicSharedMemorySize, 150656);
  k_rnn<<<1588, 512, 150656, stream>>>(whh_bf, gi2, bhh, cfb, hnT,
                                       emb, embp, embT, tcw);

  k_score<<<NPAD/64, 256, 0, stream>>>(embT, hnT, tcw, out);
}

// Round 14
// 167.680 us; speedup vs baseline: 1.2831x; 1.2831x over previous
//
#include <hip/hip_runtime.h>
#include <hip/hip_bf16.h>

#define S_LEN 50
#define BATCH 128
#define DIM 256
#define NITEMS 50001
#define NPAD 50048
#define GDIM 768
#define NSEQ 6400  // S_LEN*BATCH

typedef __attribute__((ext_vector_type(8))) short short8;
typedef __attribute__((ext_vector_type(4))) short short4_;
typedef __attribute__((ext_vector_type(4))) float float4_;

static __device__ __forceinline__ unsigned short f2bf(float x){
  union { float f; unsigned u; } v; v.f = x;
  unsigned r = v.u + 0x7FFFu + ((v.u >> 16) & 1u);
  return (unsigned short)(r >> 16);
}
static __device__ __forceinline__ float bf2f(unsigned short h){
  union { unsigned u; float f; } v; v.u = ((unsigned)h) << 16;
  return v.f;
}
static __device__ __forceinline__ float rcpf_(float x){ return __builtin_amdgcn_rcpf(x); }
static __device__ __forceinline__ float exp2f_(float x){ return __builtin_amdgcn_exp2f(x); }

// ============ prep: [0,576) whh conv | [576,720) wihT | [720,1120) xT + cfb ============
// (r12-proven) frag elem within a 16-row tile g: ((g*8 + kf)*64 + r16 + qd*16)*8 + j
__global__ __launch_bounds__(256) void k_prep(
        const float* __restrict__ wih, unsigned short* __restrict__ wihT,
        const float* __restrict__ whh, unsigned short* __restrict__ whh_bf,
        const float* __restrict__ emb, const float* __restrict__ embp,
        const int* __restrict__ seq, unsigned short* __restrict__ xT,
        float* __restrict__ cfb){
  __shared__ unsigned short sT[8192];
  int bid = blockIdx.x;
  int tid = threadIdx.x;
  if (bid < 576){
    int i = bid*256 + tid;               // 147456 float4s
    float4_ y = ((const float4_*)whh)[i];
    short4_ v;
    #pragma unroll
    for (int j=0;j<4;j++) v[j] = (short)f2bf(y[j]);
    ((short4_*)whh_bf)[i] = v;
    return;
  }
  int w = tid >> 6, lane = tid & 63;
  int r16 = w*4 + (lane >> 4);
  int c0  = lane & 15;
  if (bid < 720){
    int bx = bid - 576;                  // 0..143
    const float4_* er = (const float4_*)(wih + (size_t)(bx*16 + r16)*DIM);
    #pragma unroll
    for (int k=0;k<4;k++){
      float4_ v = er[k*16 + c0];
      short4_ o;
      #pragma unroll
      for (int jj=0;jj<4;jj++) o[jj] = (short)f2bf(v[jj]);
      int di = k*64 + c0*4;
      int kf = di >> 5, qd = (di >> 3) & 3, j = di & 7;
      *(short4_*)(sT + (kf*64 + r16 + qd*16)*8 + j) = o;
    }
    __syncthreads();
    unsigned short* dst = wihT + (size_t)bx*4096 + tid*16;
    *(short8*)(dst)     = *(const short8*)(sT + tid*16);
    *(short8*)(dst + 8) = *(const short8*)(sT + tid*16 + 8);
    return;
  }
  {
    int bx = bid - 720;                  // 0..399 = m-tile
    int wid = bx*16 + r16;               // 0..6399
    int s = wid >> 7, b = wid & 127;
    int item = seq[s*BATCH + b];
    const float4_* er = (const float4_*)(emb + (size_t)item*DIM);
    const float4_* pp = (const float4_*)embp;
    float d0=0.f, d1=0.f, d2=0.f;
    #pragma unroll
    for (int k=0;k<4;k++){
      float4_ v = er[k*16 + c0];
      short4_ o;
      #pragma unroll
      for (int jj=0;jj<4;jj++) o[jj] = (short)f2bf(v[jj]);
      int di = k*64 + c0*4;
      int kf = di >> 5, qd = (di >> 3) & 3, j = di & 7;
      *(short4_*)(sT + (kf*64 + r16 + qd*16)*8 + j) = o;
      float4_ e0 = pp[k*16 + c0], e1 = pp[64 + k*16 + c0], e2 = pp[128 + k*16 + c0];
      #pragma unroll
      for (int jj=0;jj<4;jj++){ d0 += v[jj]*e0[jj]; d1 += v[jj]*e1[jj]; d2 += v[jj]*e2[jj]; }
    }
    #pragma unroll
    for (int off=1; off<16; off<<=1){
      d0 += __shfl_xor(d0,off); d1 += __shfl_xor(d1,off); d2 += __shfl_xor(d2,off);
    }
    if (c0 == 0){
      float m = fmaxf(d0, fmaxf(d1,d2));
      float a0 = __expf((d0-m)*10.f), a1 = __expf((d1-m)*10.f), a2 = __expf((d2-m)*10.f);
      float inv = (item != 0) ? rcpf_(a0+a1+a2) : 0.f;
      float cc0 = a0*inv, cc1 = a1*inv, cc2 = a2*inv;
      cfb[wid]          = (cc0 >= 0.01f) ? cc0 : 0.f;
      cfb[NSEQ + wid]   = (cc1 >= 0.01f) ? cc1 : 0.f;
      cfb[2*NSEQ + wid] = (cc2 >= 0.01f) ? cc2 : 0.f;
    }
    __syncthreads();
    unsigned short* dst = xT + (size_t)bx*4096 + tid*16;
    *(short8*)(dst)     = *(const short8*)(sT + tid*16);
    *(short8*)(dst + 8) = *(const short8*)(sT + tid*16 + 8);
  }
}

// ---------------- k_gi: B-tiles staged in LDS, shared by 4 waves (r12-proven) ----------------
__global__ __launch_bounds__(256) void k_gi(const unsigned short* __restrict__ xT,
        const unsigned short* __restrict__ wihT, const float* __restrict__ bih,
        const float* __restrict__ bhh, unsigned short* __restrict__ gi2){
  extern __shared__ unsigned short sB[];   // 32768 elems = 64 KB
  int bid = blockIdx.x;
  int tid = threadIdx.x;
  int nb  = bid % 6;
  int rem = bid / 6;
  int yy  = rem % 100;
  int p   = rem / 100;
  const unsigned short* Bsrc = wihT + (size_t)(p*48 + nb*8)*4096;
  #pragma unroll
  for (int r = 0; r < 16; r++){
    int c16 = r*256 + tid;               // 16B-chunk 0..4095
    *(short8*)(sB + c16*8) = *(const short8*)(Bsrc + c16*8);
  }
  __syncthreads();
  int wv = tid >> 6;
  int lane = tid & 63;
  int col = lane & 15, q = lane >> 4;
  int mt = yy*4 + wv;                    // m-tile
  float4_ z4 = {0.f,0.f,0.f,0.f};
  float4_ acc[8];
  #pragma unroll
  for (int t=0;t<8;t++) acc[t] = z4;
  #pragma unroll
  for (int kf=0; kf<8; kf++){
    short8 a = *(const short8*)(xT + (((size_t)mt*8 + kf)*64 + lane)*8);
    #pragma unroll
    for (int nt=0; nt<8; nt++){
      short8 bb = *(const short8*)(sB + ((nt*8 + kf)*64 + lane)*8);
      acc[nt] = __builtin_amdgcn_mfma_f32_16x16x32_bf16(a, bb, acc[nt], 0, 0, 0);
    }
  }
  int s     = yy >> 1;
  int slice = (yy & 1)*4 + wv;
  size_t X = (size_t)(p*S_LEN + s)*8 + slice;
  int g = (nb*8) >> 4;
  #pragma unroll
  for (int nt=0; nt<8; nt++){
    int nn = nb*8 + nt;                  // n/16
    int wc = (nn >> 1) & 7;
    int tt = nn & 1;
    int n  = nn*16 + col;
    float bv = bih[p*GDIM + n] + ((g < 2) ? bhh[p*GDIM + n] : 0.f);
    short4_ ov;
    #pragma unroll
    for (int i=0;i<4;i++) ov[i] = (short)f2bf(acc[nt][i] + bv);
    *(short4_*)(gi2 + X*12288 + (size_t)(g*16 + wc*2 + tt)*256 + lane*4) = ov;
  }
}

// ---------------- k_rnn (+ folded embT/tcw on blocks >= 24) — r11/r12 proven ----------------
__global__ __launch_bounds__(512) __attribute__((amdgpu_waves_per_eu(2, 2)))
void k_rnn(const unsigned short* __restrict__ whh_bf,
         const unsigned short* __restrict__ gi2, const float* __restrict__ bhh,
         const float* __restrict__ cfb, unsigned short* __restrict__ hnT,
         const float* __restrict__ emb, const float* __restrict__ embp,
         unsigned short* __restrict__ embT, float* __restrict__ tcw){
  extern __shared__ char lds[];
  int bid = blockIdx.x;
  int tid = threadIdx.x;
  if (bid >= 24){
    int sub = tid >> 8;
    int t2  = tid & 255;
    unsigned short* sT = (unsigned short*)lds + sub*8192;
    int w = t2 >> 6, lane = t2 & 63;
    int r16 = w*4 + (lane >> 4);
    int c0  = lane & 15;
    int bx2 = (bid - 24)*2 + sub;        // 0..3127
    int row = bx2*16 + r16;
    bool valid = row < NITEMS;
    const float4_* er = (const float4_*)(emb + (size_t)row*DIM);
    const float4_* pp = (const float4_*)embp;
    float d0=0.f, d1=0.f, d2=0.f;
    #pragma unroll
    for (int k=0;k<4;k++){
      float4_ v = valid ? er[k*16 + c0] : float4_{0.f,0.f,0.f,0.f};
      short4_ o;
      #pragma unroll
      for (int jj=0;jj<4;jj++) o[jj] = (short)f2bf(v[jj]);
      int di = k*64 + c0*4;
      int kf = di >> 5, qd = (di >> 3) & 3, j = di & 7;
      *(short4_*)(sT + (kf*64 + r16 + qd*16)*8 + j) = o;
      float4_ e0 = pp[k*16 + c0], e1 = pp[64 + k*16 + c0], e2 = pp[128 + k*16 + c0];
      #pragma unroll
      for (int jj=0;jj<4;jj++){ d0 += v[jj]*e0[jj]; d1 += v[jj]*e1[jj]; d2 += v[jj]*e2[jj]; }
    }
    #pragma unroll
    for (int off=1; off<16; off<<=1){
      d0 += __shfl_xor(d0,off); d1 += __shfl_xor(d1,off); d2 += __shfl_xor(d2,off);
    }
    if (c0 == 0 && valid){
      float m = fmaxf(d0, fmaxf(d1,d2));
      float a0 = __expf(d0-m), a1 = __expf(d1-m), a2 = __expf(d2-m);
      float inv = rcpf_(a0+a1+a2);
      tcw[row*3+0] = a0*inv; tcw[row*3+1] = a1*inv; tcw[row*3+2] = a2*inv;
    }
    __syncthreads();
    unsigned short* dst = embT + (size_t)bx2*4096 + t2*16;
    *(short8*)(dst)     = *(const short8*)(sT + t2*16);
    *(short8*)(dst + 8) = *(const short8*)(sT + t2*16 + 8);
    return;
  }
  // ---- PSRU recurrence (r9 config, unchanged) ----
  float* cfs = (float*)(lds + 147456);
  int p  = bid >> 3;
  int slice = bid & 7;
  int b0 = slice * 16;
  int w = tid >> 6, lane = tid & 63;
  int col = lane & 15;
  int q = lane >> 4;
  int kq = q * 8;
  const unsigned short* Wp = whh_bf + (size_t)p*GDIM*DIM;

  for (int i = tid; i < 8192; i += 512) ((unsigned short*)lds)[i] = 0;
  for (int i = tid; i < 800; i += 512) cfs[i] = cfb[p*NSEQ + (i>>4)*BATCH + b0 + (i&15)];
  {
    const unsigned short* Wn = Wp + (size_t)512*DIM;
    #pragma unroll
    for (int r = 0; r < 16; r++){
      int j = r*512 + tid;          // 0..8191
      int kf = j >> 10, row = (j >> 2) & 255, qs = j & 3;
      short8 v = *(const short8*)(Wn + (size_t)row*DIM + kf*32 + ((qs ^ ((row>>1)&3)) << 3));
      *(short8*)(lds + 16384 + j*16) = v;
    }
  }

  float bias_n0 = bhh[p*GDIM + 512 + w*32 + col];
  float bias_n1 = bhh[p*GDIM + 512 + w*32 + 16 + col];

  short8 Bf[8][4];
  #pragma unroll
  for (int kf=0; kf<8; kf++){
    #pragma unroll
    for (int t=0;t<4;t++){
      int gc = (t>>1)*256 + w*32 + (t&1)*16 + col;
      Bf[kf][t] = *(const short8*)(Wp + ((size_t)gc << 8) + kf*32 + kq);
      asm volatile("" : "+a"(Bf[kf][t]));
    }
  }
  const char* wn0 = lds + 16384 + (size_t)(w*32 + col)*64 + ((q ^ ((col>>1)&3)) << 4);
  const char* wn1 = wn0 + 16*64;
  int swz  = (lane & 7) << 4;   // h-buffer swizzle (row = col)
  float hreg[2][4];
  #pragma unroll
  for (int t=0;t<2;t++){
    #pragma unroll
    for (int i=0;i<4;i++) hreg[t][i] = 0.f;
  }
  const size_t GSTRIDE = (size_t)8*12288;
  const unsigned short* gbase =
      gi2 + ((size_t)p*S_LEN*8 + slice)*12288 + (size_t)(w*2)*256 + lane*4;
  short4_ cur[6], nxt[6];
  #pragma unroll
  for (int t=0;t<6;t++)
    cur[t] = *(const short4_*)(gbase + (t>>1)*4096 + (t&1)*256);
  __syncthreads();

  const float K1 = -1.442695041f;   // -log2(e)
  const float K2 =  2.885390082f;   // 2*log2(e)
  float4_ z4 = {0.f,0.f,0.f,0.f};
  for (int s = 0; s < S_LEN; s++){
    int rbuf = s & 1, wbuf = rbuf ^ 1;
    int sn = (s+1 < S_LEN) ? s+1 : 0;
    const unsigned short* gnp = gbase + (size_t)sn*GSTRIDE;
    #pragma unroll
    for (int t=0;t<6;t++)
      nxt[t] = *(const short4_*)(gnp + (t>>1)*4096 + (t&1)*256);
    float4_ acc[6];
    #pragma unroll
    for (int t=0;t<6;t++) acc[t] = z4;
    const char* hrow = lds + rbuf*8192 + col*512;
    #pragma unroll
    for (int kf=0; kf<8; kf++){
      int ko = (kf*64 + q*16);
      short8 a = *(const short8*)(hrow + (ko ^ swz));
      #pragma unroll
      for (int t=0;t<4;t++)
        acc[t] = __builtin_amdgcn_mfma_f32_16x16x32_bf16(a, Bf[kf][t], acc[t], 0, 0, 0);
      short8 b4 = *(const short8*)(wn0 + kf*16384);
      acc[4] = __builtin_amdgcn_mfma_f32_16x16x32_bf16(a, b4, acc[4], 0, 0, 0);
      short8 b5 = *(const short8*)(wn1 + kf*16384);
      acc[5] = __builtin_amdgcn_mfma_f32_16x16x32_bf16(a, b5, acc[5], 0, 0, 0);
    }
    float4_ cfv = *(const float4_*)(cfs + s*16 + 4*q);
    char* wbase = lds + wbuf*8192;
    int d0b = 2*(w*32 + col);
    #pragma unroll
    for (int i=0;i<4;i++){
      int rb = 4*q + i;
      float hy01[2];
      #pragma unroll
      for (int t=0;t<2;t++){
        float bn = t ? bias_n1 : bias_n0;
        float r = rcpf_(1.f + exp2f_(K1*(bf2f((unsigned short)cur[t][i])   + acc[t][i])));
        float z = rcpf_(1.f + exp2f_(K1*(bf2f((unsigned short)cur[2+t][i]) + acc[2+t][i])));
        float pre = bf2f((unsigned short)cur[4+t][i]) + r*(acc[4+t][i] + bn);
        float n = 1.f - 2.f*rcpf_(exp2f_(K2*pre) + 1.f);
        float ho = hreg[t][i];
        float hy = ho - cfv[i]*z*(ho - n);
        hreg[t][i] = hy;
        hy01[t] = hy;
      }
      unsigned pk;
      asm("v_cvt_pk_bf16_f32 %0, %1, %2" : "=v"(pk) : "v"(hy01[0]), "v"(hy01[1]));
      char* rowp = wbase + rb*512;
      int sw = (rb & 7) << 4;
      *(unsigned short*)(rowp + (d0b ^ sw))        = (unsigned short)pk;
      *(unsigned short*)(rowp + ((d0b + 32) ^ sw)) = (unsigned short)(pk >> 16);
    }
    #pragma unroll
    for (int t=0;t<6;t++) cur[t] = nxt[t];
    __syncthreads();
  }
  #pragma unroll
  for (int t=0; t<2; t++){
    int d  = w*32 + t*16 + col;
    int kf = d >> 5;
    int qd = (d >> 3) & 3;
    int j  = d & 7;
    #pragma unroll
    for (int i=0; i<4; i++){
      int rb = 4*q + i;
      hnT[(((size_t)p*8 + slice)*8 + kf)*512 + (size_t)(rb + qd*16)*8 + j] = f2bf(hreg[t][i]);
    }
  }
}

// ---------------- k_score v2: hnT staged in LDS per kf-slice, shared by 4 waves ----------------
// All 4 waves read the SAME hnT (they differ only in embT tile): per kf, stage
// the 24 fragments (24KB) cooperatively, MFMA from LDS -> hnT L2 traffic
// 768KB -> 192KB per block (600 -> 150 MB total). Staging buffer aliases the
// 33KB output-staging sm (staging done before sm written; barrier between).
__global__ __launch_bounds__(256) void k_score(const unsigned short* __restrict__ embT,
        const unsigned short* __restrict__ hnT, const float* __restrict__ tcw,
        float* __restrict__ out){
  __shared__ float sm[64*129];
  unsigned short* sA = (unsigned short*)sm;   // 24KB staging alias
  int tid = threadIdx.x;
  int w = tid >> 6, lane = tid & 63;
  int col = lane & 15, q = lane >> 4;
  int t16 = blockIdx.x*4 + w;
  int trow = t16*16 + col;
  float4_ z4 = {0.f,0.f,0.f,0.f};
  float4_ acc[3][8];
  #pragma unroll
  for (int p=0;p<3;p++){
    #pragma unroll
    for (int m=0;m<8;m++) acc[p][m] = z4;
  }
  #pragma unroll
  for (int kf=0; kf<8; kf++){
    __syncthreads();
    // stage 24 frags x 1024B = 1536 16B-chunks
    #pragma unroll
    for (int r=0;r<6;r++){
      int c = r*256 + tid;               // 0..1535
      int f = c >> 6, l = c & 63;
      *(short8*)(sA + (size_t)c*8) = *(const short8*)(hnT + ((size_t)f*8 + kf)*512 + l*8);
    }
    __syncthreads();
    short8 bb = *(const short8*)(embT + (((size_t)t16*8 + kf)*64 + lane)*8);
    #pragma unroll
    for (int p=0;p<3;p++){
      #pragma unroll
      for (int m=0;m<8;m++){
        short8 a = *(const short8*)(sA + ((p*8 + m)*64 + lane)*8);
        acc[p][m] = __builtin_amdgcn_mfma_f32_16x16x32_bf16(a, bb, acc[p][m], 0, 0, 0);
      }
    }
  }
  float w0=0.f, w1=0.f, w2=0.f;
  if (trow < NITEMS){ w0 = tcw[trow*3+0]; w1 = tcw[trow*3+1]; w2 = tcw[trow*3+2]; }
  __syncthreads();
  #pragma unroll
  for (int m=0;m<8;m++){
    #pragma unroll
    for (int i=0;i<4;i++){
      sm[(w*16 + col)*129 + m*16 + 4*q + i] =
          w0*acc[0][m][i] + w1*acc[1][m][i] + w2*acc[2][m][i];
    }
  }
  __syncthreads();
  int trowW = blockIdx.x*64 + lane;
  if (trowW < NITEMS){
    float* orow = out + trowW;
    #pragma unroll 4
    for (int c=0; c<32; c++){
      int b = w*32 + c;
      orow[(size_t)b*NITEMS] = sm[lane*129 + b];
    }
  }
}

extern "C" void kernel_launch(void* const* d_in, const int* in_sizes, int n_in,
                              void* d_out, int out_size, void* d_ws, size_t ws_size,
                              hipStream_t stream) {
  const int*   seq  = (const int*)d_in[0];
  const float* emb  = (const float*)d_in[1];
  const float* embp = (const float*)d_in[2];
  const float* wih  = (const float*)d_in[3];
  const float* whh  = (const float*)d_in[4];
  const float* bih  = (const float*)d_in[5];
  const float* bhh  = (const float*)d_in[6];
  float* out = (float*)d_out;

  char* ws = (char*)d_ws;
  size_t off = 0;
  auto alloc = [&](size_t bytes) -> void* {
    void* r = ws + off; off += (bytes + 255) & ~(size_t)255; return r;
  };
  unsigned short* embT   = (unsigned short*)alloc((size_t)NPAD*DIM*2);
  unsigned short* xT     = (unsigned short*)alloc((size_t)NSEQ*DIM*2);
  unsigned short* wihT   = (unsigned short*)alloc((size_t)3*GDIM*DIM*2);
  unsigned short* whh_bf = (unsigned short*)alloc((size_t)3*GDIM*DIM*2);
  unsigned short* gi2    = (unsigned short*)alloc((size_t)3*NSEQ*GDIM*2);
  float* tcw = (float*)alloc((size_t)NITEMS*3*4);
  float* cfb = (float*)alloc((size_t)3*NSEQ*4);
  unsigned short* hnT = (unsigned short*)alloc((size_t)3*BATCH*DIM*2);

  k_prep<<<1120, 256, 0, stream>>>(wih, wihT, whh, whh_bf, emb, embp, seq, xT, cfb);

  (void)hipFuncSetAttribute((const void*)k_gi,
        hipFuncAttributeMaxDynamicSharedMemorySize, 65536);
  k_gi<<<1800, 256, 65536, stream>>>(xT, wihT, bih, bhh, gi2);

  (void)hipFuncSetAttribute((const void*)k_rnn,
        hipFuncAttributeMaxDynamicSharedMemorySize, 150656);
  k_rnn<<<1588, 512, 150656, stream>>>(whh_bf, gi2, bhh, cfb, hnT,
                                       emb, embp, embT, tcw);

  k_score<<<NPAD/64, 256, 0, stream>>>(embT, hnT, tcw, out);
}